// Round 6
// baseline (1307.514 us; speedup 1.0000x reference)
//
#include <hip/hip_runtime.h>
#include <math.h>

#define NB 32        // batches
#define NP 512       // N == M == 512
#define RG 8         // row-groups (blocks) per batch
#define RPB 64       // rows per block
#define ITERS 50
#define EPSV   0.05f
#define INVEPS 20.0f

typedef unsigned long long u64;
typedef unsigned int u32;

// ws layout: pack[2][NB][RG][NP] u32 (row-major: each 512-col stream is a
// contiguous single-writer array -> no false sharing), then epi[NB][RG] float2.
// Poison safety: 0xAAAAAAAA low 3 bits = 2; tag set {1,3,4,5,6,7} never
// contains 2 and all tags within a 6-window are distinct. epi tag 51.0f.
// Cross-dispatch staleness: dispatch-boundary cache invalidation (empirically
// confirmed by R1 passing: k=1 tag==k=49 tag of prior dispatch, no false
// accept) + poison re-write make k=1/2 reads poison-tagged, never stale-valid.
#define N_PACK (2*NB*RG*NP)
#define PAR_STRIDE (NB*RG*NP)      // 131072 u32 per parity buffer

// ---- agent-scope (device-coherent, IC) primitives — cross-XCD safe ----
__device__ __forceinline__ void st32(u32* p, u32 v) {
  __hip_atomic_store(p, v, __ATOMIC_RELAXED, __HIP_MEMORY_SCOPE_AGENT);
}
__device__ __forceinline__ u32 ld32(const u32* p) {
  return __hip_atomic_load(p, __ATOMIC_RELAXED, __HIP_MEMORY_SCOPE_AGENT);
}
__device__ __forceinline__ void st64f(float2* p, float tag, float val) {
  union { float2 f; u64 u; } c; c.f = make_float2(tag, val);
  __hip_atomic_store((u64*)p, c.u, __ATOMIC_RELAXED, __HIP_MEMORY_SCOPE_AGENT);
}
__device__ __forceinline__ float2 ld64f(const float2* p) {
  union { u64 u; float2 f; } c;
  c.u = __hip_atomic_load((const u64*)p, __ATOMIC_RELAXED, __HIP_MEMORY_SCOPE_AGENT);
  return c.f;
}

// ---- XCD-local fast-path primitives (same-XCD proven by R1's FETCH collapse)
__device__ __forceinline__ void st32_l2(u32* p, u32 v) {
  // plain store: write-through L1 -> lands in the shared per-XCD L2
  asm volatile("global_store_dword %0, %1, off" :: "v"(p), "v"(v) : "memory");
}
// gang-issue 7 sc0 loads, NO wait (speculative top-of-iteration issue)
__device__ __forceinline__ void ld7_issue(
    const u32* p0, const u32* p1, const u32* p2, const u32* p3,
    const u32* p4, const u32* p5, const u32* p6,
    u32& q0, u32& q1, u32& q2, u32& q3, u32& q4, u32& q5, u32& q6) {
  asm volatile(
    "global_load_dword %0, %7, off sc0\n\t"
    "global_load_dword %1, %8, off sc0\n\t"
    "global_load_dword %2, %9, off sc0\n\t"
    "global_load_dword %3, %10, off sc0\n\t"
    "global_load_dword %4, %11, off sc0\n\t"
    "global_load_dword %5, %12, off sc0\n\t"
    "global_load_dword %6, %13, off sc0"
    : "=&v"(q0), "=&v"(q1), "=&v"(q2), "=&v"(q3),
      "=&v"(q4), "=&v"(q5), "=&v"(q6)
    : "v"(p0), "v"(p1), "v"(p2), "v"(p3), "v"(p4), "v"(p5), "v"(p6)
    : "memory");
}
// gang-issue 7 sc0 loads + single wait: one shared-L2 RT per sweep
__device__ __forceinline__ void ld7_l2(
    const u32* p0, const u32* p1, const u32* p2, const u32* p3,
    const u32* p4, const u32* p5, const u32* p6,
    u32& q0, u32& q1, u32& q2, u32& q3, u32& q4, u32& q5, u32& q6) {
  asm volatile(
    "global_load_dword %0, %7, off sc0\n\t"
    "global_load_dword %1, %8, off sc0\n\t"
    "global_load_dword %2, %9, off sc0\n\t"
    "global_load_dword %3, %10, off sc0\n\t"
    "global_load_dword %4, %11, off sc0\n\t"
    "global_load_dword %5, %12, off sc0\n\t"
    "global_load_dword %6, %13, off sc0\n\t"
    "s_waitcnt vmcnt(0)"
    : "=&v"(q0), "=&v"(q1), "=&v"(q2), "=&v"(q3),
      "=&v"(q4), "=&v"(q5), "=&v"(q6)
    : "v"(p0), "v"(p1), "v"(p2), "v"(p3), "v"(p4), "v"(p5), "v"(p6)
    : "memory");
}

// tag for iteration k: nibble LUT over k%6 -> {1,3,4,5,6,7}; all tags in any
// 6-window distinct, so tag(k) != tag(k-1) != tag(k-2) (stale detect exact)
__device__ __forceinline__ u32 tag_of(int k) {
  return (0x765431u >> (4 * (k % 6))) & 0xFu;
}
// pack fp32 value with tag in low 3 mantissa bits (<=7 ulp perturbation)
__device__ __forceinline__ u32 pack_slot(float v, u32 tag) {
  return (__float_as_uint(v) & ~7u) | tag;
}

// ---------------- single fused kernel: setup + 50 linear-Sinkhorn iters + ot ----
// ONE batch per 512-thread block, 64 rows each, RG=8 blocks/batch, grid=256
// (1 block/CU, all resident -> spin rendezvous deadlock-free).
//
// R6 = R0's proven loop + the L2 medium ALONE (R1 minus its baggage).
// Evidence: R1 proved XCD-co-location + plain-store/sc0-load works (FETCH
// 95.6->14.0 MB, correct); its +13us came from every-4th agent gangs and
// per-sweep vmcnt(0) stalling on own agent-store acks. R3/R5 falsified
// congestion and sampling-period theories. R6:
//  - publish: plain store (shared L2, fast path) + agent store (IC, truth
//    for the cross-XCD fallback; same bits -> any order benign).
//  - spec issue at top = sc0 gang, no wait; consumed after vmcnt(2) (waits
//    the 7 loads, not the 2 stores — oldest-first vmcnt) + sched_barrier.
//  - own-store ack drained ONCE (only if spec misses); sweeps are then pure
//    L2 RTs (ld7 gang + vmcnt(0)).
//  - liveness: after 64 L2 sweeps, pending streams also poll agent-scope
//    (IC) — R0's transport — via the same tag check. Broken mapping
//    degrades to ~R0 speed; never hangs; never accepts stale.
__global__ __launch_bounds__(NP) void emd_kernel(
    const float* __restrict__ a_mask, const float* __restrict__ pc_a,
    const float* __restrict__ b_mask, const float* __restrict__ pc_b,
    u32* __restrict__ pack, float2* __restrict__ epi,
    float* __restrict__ out)
{
  const int rb = blockIdx.x;
  // XCD-local decode: rb%8 = b%8 -> all 8 blocks of a batch on one XCD
  // under round-robin dispatch (evidence: R1's FETCH collapse).
  const int xc = rb & 7;
  const int qq = rb >> 3;            // 0..31
  const int rg = qq >> 2;            // row-group 0..7
  const int b  = ((qq & 3) << 3) | xc;  // batch 0..31
  const int t  = threadIdx.x;
  const int chunk = t & 7;           // 8 threads per row
  const int lrow  = t >> 3;          // local row 0..63
  const int grow  = rg*RPB + lrow;
  const int lane  = t & 63, wid = t >> 6;

  __shared__ __align__(16) float rho_l[NP];   // exp(logv)
  __shared__ __align__(16) float bw_l[NP];    // col masses
  __shared__ __align__(16) float u_l[RPB];    // exp(logu)
  __shared__ __align__(16) float sm[NP];      // setup aw / epilogue scratch
  __shared__ float red[16];

  float4 eKreg[16];     // row slice: row=grow, cols 32*cc+4*chunk+e
  float  eKcol[RPB];    // col slice: col=t, rows rg*64+i
  float  aw_r, bw_t, hub = 0.f;

  // stream pointers
  #define RIDX(i) ((i) + ((i) >= rg ? 1 : 0))
  const u32* base0 = pack + (size_t)b*RG*NP + t;
  u32* ownp = pack + ((size_t)(b*RG + rg))*NP + t;
  const u32* p0 = base0 + (size_t)RIDX(0)*NP;
  const u32* p1 = base0 + (size_t)RIDX(1)*NP;
  const u32* p2 = base0 + (size_t)RIDX(2)*NP;
  const u32* p3 = base0 + (size_t)RIDX(3)*NP;
  const u32* p4 = base0 + (size_t)RIDX(4)*NP;
  const u32* p5 = base0 + (size_t)RIDX(5)*NP;
  const u32* p6 = base0 + (size_t)RIDX(6)*NP;

  // ================= setup: masses, huber, expK caches =================
  {
    const float apt = a_mask[b*NP+t] * pc_a[((size_t)b*NP+t)*3+2];
    const float bpt = b_mask[b*NP+t] * pc_b[((size_t)b*NP+t)*3+2];
    float ra = apt, rv = bpt;
    #pragma unroll
    for (int o = 32; o; o >>= 1) { ra += __shfl_xor(ra, o); rv += __shfl_xor(rv, o); }
    if (lane == 0) { red[wid] = ra; red[8+wid] = rv; }
    __syncthreads();
    float asum = 0.f, bsum = 0.f;
    #pragma unroll
    for (int w = 0; w < 8; ++w) { asum += red[w]; bsum += red[8+w]; }
    const float e = asum - bsum, ae = fabsf(e);
    hub = (ae <= 1.f) ? 0.5f*e*e : (ae - 0.5f);
    sm[t]   = (apt > 0.f) ? apt/asum : 0.f;   // aw
    bw_l[t] = (bpt > 0.f) ? bpt/bsum : 0.f;
    __syncthreads();
    aw_r = sm[grow];
    bw_t = bw_l[t];
    const float ax = pc_a[((size_t)b*NP+grow)*3+0];
    const float ay = pc_a[((size_t)b*NP+grow)*3+1];
    const bool  va = aw_r > 0.f;
    #pragma unroll
    for (int cc = 0; cc < 16; ++cc) {
      float r[4];
      #pragma unroll
      for (int e2 = 0; e2 < 4; ++e2) {
        const int col = 32*cc + 4*chunk + e2;
        const float bx = pc_b[((size_t)b*NP+col)*3+0];
        const float by = pc_b[((size_t)b*NP+col)*3+1];
        const bool  vb = bw_l[col] > 0.f;
        const float dx = ax-bx, dy = ay-by;
        const float d  = sqrtf(dx*dx + dy*dy + 1e-12f);
        r[e2] = (va && vb) ? __expf((-INVEPS)*d) : 1.f;   // K=0 for masked pairs
      }
      eKreg[cc] = make_float4(r[0], r[1], r[2], r[3]);
    }
    const float bx0 = pc_b[((size_t)b*NP+t)*3+0];
    const float by0 = pc_b[((size_t)b*NP+t)*3+1];
    const bool  vb0 = bw_t > 0.f;
    #pragma unroll
    for (int i = 0; i < RPB; ++i) {
      const int row = rg*RPB + i;
      const float axi = pc_a[((size_t)b*NP+row)*3+0];  // wave-uniform -> scalar loads
      const float ayi = pc_a[((size_t)b*NP+row)*3+1];
      const bool  vai = sm[row] > 0.f;
      const float dx = axi-bx0, dy = ayi-by0;
      const float d  = sqrtf(dx*dx + dy*dy + 1e-12f);
      eKcol[i] = (vai && vb0) ? __expf((-INVEPS)*d) : 1.f;
    }
    rho_l[t] = 1.f;     // rho(0) = exp(logv=0) = 1
    __syncthreads();
  }

  // accept-if-fresh check for stream i (pend-guarded; single writer per k)
  #define CHK(i, qv, vv) \
    if ((pend >> (i)) & 1u) { if (((qv) & 7u) == tag) { vv = (qv); pend &= ~(1u << (i)); } }

  // ================= main loop =================
  for (int k = 1; k <= ITERS; ++k) {
    const u32 tag = tag_of(k);
    const size_t po = (size_t)(k & 1) * (size_t)PAR_STRIDE;
    u32 q0, q1, q2, q3, q4, q5, q6;

    // ---- speculative early issue (sc0, no wait) — overlaps with B+C;
    // peers that ran ahead are discovered for free; tag(k)!=tag(k-2) exact.
    ld7_issue(p0+po, p1+po, p2+po, p3+po, p4+po, p5+po, p6+po,
              q0, q1, q2, q3, q4, q5, q6);

    // ---- B: u(k) = aw / sum_j ek*rho(k-1)
    {
      const float4* r4p = (const float4*)rho_l;
      float dot = 0.f;
      #pragma unroll
      for (int cc = 0; cc < 16; ++cc) {
        const float4 g4 = r4p[8*cc + chunk];
        const float4 kk = eKreg[cc];
        dot += kk.x*g4.x + kk.y*g4.y + kk.z*g4.z + kk.w*g4.w;
      }
      #pragma unroll
      for (int o = 4; o; o >>= 1) dot += __shfl_xor(dot, o);   // 8-lane row reduce
      if (chunk == 0) u_l[lrow] = aw_r / fmaxf(dot, 1e-38f);
    }
    __syncthreads();   // u_l ready (also: all rho_l reads done)

    // ---- C: publish packed col partial s(k) for col t; keep own value local
    float sc_own;
    {
      const float4* u4p = (const float4*)u_l;
      float sc = 0.f;
      #pragma unroll
      for (int i4 = 0; i4 < 16; ++i4) {
        const float4 uu = u4p[i4];
        sc += eKcol[4*i4+0]*uu.x + eKcol[4*i4+1]*uu.y
            + eKcol[4*i4+2]*uu.z + eKcol[4*i4+3]*uu.w;
      }
      sc_own = sc;
      const u32 w = pack_slot(sc, tag);
      u32* os = ownp + po;
      st32_l2(os, w);    // plain -> shared per-XCD L2 (fast path)
      st32(os, w);       // agent -> IC (cross-XCD fallback truth; same bits)
    }

    // ---- A: consume spec loads, then L2-sweep; agent fallback after 64.
    {
      u32 v0=0, v1=0, v2=0, v3=0, v4=0, v5=0, v6=0;
      unsigned pend = 0x7Fu;
      // vmcnt(2): waits the 7 spec loads, not our 2 newest ops (the stores)
      asm volatile("s_waitcnt vmcnt(2)" ::: "memory");
      __builtin_amdgcn_sched_barrier(0);
      CHK(0,q0,v0) CHK(1,q1,v1) CHK(2,q2,v2) CHK(3,q3,v3)
      CHK(4,q4,v4) CHK(5,q5,v5) CHK(6,q6,v6)
      if (pend) {
        // drain own publish acks ONCE so sweeps are pure L2 RTs
        asm volatile("s_waitcnt vmcnt(0)" ::: "memory");
        __builtin_amdgcn_sched_barrier(0);
        int sweeps = 0;
        while (true) {
          ld7_l2(p0+po, p1+po, p2+po, p3+po, p4+po, p5+po, p6+po,
                 q0, q1, q2, q3, q4, q5, q6);
          CHK(0,q0,v0) CHK(1,q1,v1) CHK(2,q2,v2) CHK(3,q3,v3)
          CHK(4,q4,v4) CHK(5,q5,v5) CHK(6,q6,v6)
          if (!pend) break;
          ++sweeps;
          if (sweeps > 64) {
            // liveness under any mapping: agent (IC) polls carry the data
            u32 x;
            if (pend & 0x01u) { x = ld32(p0+po); if ((x&7u)==tag){v0=x; pend&=~0x01u;} }
            if (pend & 0x02u) { x = ld32(p1+po); if ((x&7u)==tag){v1=x; pend&=~0x02u;} }
            if (pend & 0x04u) { x = ld32(p2+po); if ((x&7u)==tag){v2=x; pend&=~0x04u;} }
            if (pend & 0x08u) { x = ld32(p3+po); if ((x&7u)==tag){v3=x; pend&=~0x08u;} }
            if (pend & 0x10u) { x = ld32(p4+po); if ((x&7u)==tag){v4=x; pend&=~0x10u;} }
            if (pend & 0x20u) { x = ld32(p5+po); if ((x&7u)==tag){v5=x; pend&=~0x20u;} }
            if (pend & 0x40u) { x = ld32(p6+po); if ((x&7u)==tag){v6=x; pend&=~0x40u;} }
            if (!pend) break;
          }
          if (sweeps > (1<<22)) break;   // fail visibly, never hang
        }
      }
      float S = sc_own
              + __uint_as_float(v0) + __uint_as_float(v1) + __uint_as_float(v2)
              + __uint_as_float(v3) + __uint_as_float(v4) + __uint_as_float(v5)
              + __uint_as_float(v6);                      // <=7 ulp tag noise
      rho_l[t] = bw_t / fmaxf(S, 1e-38f);
    }
    __syncthreads();   // rho_l(k) ready for next B / epilogue
  }

  // ---- epilogue: ot partial = sum d^2 * u_i * ek * rho_j over my row slice
  float acc = 0.f;
  {
    const float ur = u_l[lrow];                  // u(50)
    const float4* r4p = (const float4*)rho_l;    // rho(50)
    #pragma unroll
    for (int cc = 0; cc < 16; ++cc) {
      const float4 g4 = r4p[8*cc + chunk];
      const float4 kk = eKreg[cc];
      const float ek[4] = {kk.x, kk.y, kk.z, kk.w};
      const float vv[4] = {g4.x, g4.y, g4.z, g4.w};
      #pragma unroll
      for (int e2 = 0; e2 < 4; ++e2) {
        const float lk = __logf(fmaxf(ek[e2], 1e-38f));  // d = -EPS*lk; masked: lk=0 -> d2=0
        const float d2 = (EPSV*lk)*(EPSV*lk);
        const float v  = d2 * ur * ek[e2] * vv[e2];
        acc += (ek[e2] > 0.f) ? v : 0.f;
      }
    }
  }
  // block-reduce, publish tagged epi, rg==0 gathers (agent scope, one-time)
  sm[t] = acc;
  __syncthreads();
  if (t < 64) {
    float v = 0.f;
    #pragma unroll
    for (int q = 0; q < 8; ++q) v += sm[t*8+q];
    #pragma unroll
    for (int o = 32; o; o >>= 1) v += __shfl_xor(v, o);
    if (t == 0) st64f(epi + (size_t)b*RG + rg, 51.f, v);
  }
  if (rg == 0 && t < RG) {     // gather: 8 lanes, poll + shfl-reduce
    float2 pr;
    long long spins = 0;
    do {
      pr = ld64f(epi + (size_t)b*RG + t);
      if (pr.x == 51.f) break;
      __builtin_amdgcn_s_sleep(1);
    } while (++spins < (1LL<<26));
    float v = pr.y;
    #pragma unroll
    for (int o = 4; o; o >>= 1) v += __shfl_xor(v, o);
    if (t == 0) out[b] = v + hub;
  }
}

extern "C" void kernel_launch(void* const* d_in, const int* in_sizes, int n_in,
                              void* d_out, int out_size, void* d_ws, size_t ws_size,
                              hipStream_t stream) {
  const float* a_mask = (const float*)d_in[0];
  const float* pc_a   = (const float*)d_in[1];
  const float* b_mask = (const float*)d_in[2];
  const float* pc_b   = (const float*)d_in[3];
  float* out = (float*)d_out;
  u32*    pack = (u32*)d_ws;                 // 1 MiB
  float2* epi  = (float2*)(pack + N_PACK);   // + 2 KiB
  (void)in_sizes; (void)n_in; (void)out_size; (void)ws_size;

  emd_kernel<<<NB*RG, NP, 0, stream>>>(a_mask, pc_a, b_mask, pc_b,
                                       pack, epi, out);
}

// Round 7
// 195.988 us; speedup vs baseline: 6.6714x; 6.6714x over previous
//
#include <hip/hip_runtime.h>
#include <math.h>

#define NB 32        // batches
#define NP 512       // N == M == 512
#define RG 8         // row-groups (blocks) per batch
#define RPB 64       // rows per block
#define ITERS 50
#define EPSV   0.05f
#define INVEPS 20.0f

typedef unsigned long long u64;
typedef unsigned int u32;

// ws layout: pack[2][NB][RG][NP] u32 (row-major: each 512-col stream is a
// contiguous single-writer array -> no false sharing), then epi[NB][RG] float2.
// Poison safety: 0xAAAAAAAA low 3 bits = 2; tag set {1,3,4,5,6,7} never
// contains 2 and tag(k) != tag(k-2) (k mod 6 LUT). epi tag 51.0f != poison.
#define N_PACK (2*NB*RG*NP)

// ---- relaxed agent-scope (device-coherent, IC) primitives ----
// R6 proved this is the ONLY working CU-to-CU transport on gfx950:
// plain-store/sc0-load pairs serve stale hits indefinitely (1307us).
__device__ __forceinline__ void st32(u32* p, u32 v) {
  __hip_atomic_store(p, v, __ATOMIC_RELAXED, __HIP_MEMORY_SCOPE_AGENT);
}
__device__ __forceinline__ u32 ld32(const u32* p) {
  return __hip_atomic_load(p, __ATOMIC_RELAXED, __HIP_MEMORY_SCOPE_AGENT);
}
__device__ __forceinline__ void st64f(float2* p, float tag, float val) {
  union { float2 f; u64 u; } c; c.f = make_float2(tag, val);
  __hip_atomic_store((u64*)p, c.u, __ATOMIC_RELAXED, __HIP_MEMORY_SCOPE_AGENT);
}
__device__ __forceinline__ float2 ld64f(const float2* p) {
  union { u64 u; float2 f; } c;
  c.u = __hip_atomic_load((const u64*)p, __ATOMIC_RELAXED, __HIP_MEMORY_SCOPE_AGENT);
  return c.f;
}

// tag for iteration k: nibble LUT over k%6 -> {1,3,4,5,6,7} (proven r12/r14)
__device__ __forceinline__ u32 tag_of(int k) {
  return (0x765431u >> (4 * (k % 6))) & 0xFu;
}
// pack fp32 value with tag in low 3 mantissa bits (<=7 ulp perturbation)
__device__ __forceinline__ u32 pack_slot(float v, u32 tag) {
  return (__float_as_uint(v) & ~7u) | tag;
}

// ---------------- single fused kernel: setup + 50 linear-Sinkhorn iters + ot ----
// ONE batch per 512-thread block, 64 rows each, RG=8 blocks/batch, grid=256
// (1 block/CU, all resident -> spin rendezvous deadlock-free).
//
// R7 = R0 (proven champion, 153.7us) with ONE timing change: the speculative
// gang of 7 remote loads is issued immediately AFTER our own publish instead
// of at the iteration top. Rationale (R0-R6 falsification program): transport
// = agent/IC only (R6); congestion (R3), sampling period (R5), and medium
// (R1/R6) all falsified. R0's top-of-iteration sample is taken ~600cy before
// any near-lockstep peer can have published iteration k, so it is stale by
// construction and forces >=1 extra full re-sweep. Post-publish issue samples
// the IC exactly when peers publish -> first check catches most peers.
__global__ __launch_bounds__(NP) void emd_kernel(
    const float* __restrict__ a_mask, const float* __restrict__ pc_a,
    const float* __restrict__ b_mask, const float* __restrict__ pc_b,
    u32* __restrict__ pack, float2* __restrict__ epi,
    float* __restrict__ out)
{
  const int rb = blockIdx.x;
  const int b  = rb >> 3;            // batch (contiguous 8-block ranges, R0 decode)
  const int rg = rb & 7;             // row-group 0..7
  const int t  = threadIdx.x;
  const int chunk = t & 7;           // 8 threads per row
  const int lrow  = t >> 3;          // local row 0..63
  const int grow  = rg*RPB + lrow;
  const int lane  = t & 63, wid = t >> 6;

  __shared__ __align__(16) float rho_l[NP];   // exp(logv)
  __shared__ __align__(16) float bw_l[NP];    // col masses
  __shared__ __align__(16) float u_l[RPB];    // exp(logu)
  __shared__ __align__(16) float sm[NP];      // setup aw / epilogue scratch
  __shared__ float red[16];

  float4 eKreg[16];     // row slice: row=grow, cols 32*cc+4*chunk+e
  float  eKcol[RPB];    // col slice: col=t, rows rg*64+i
  float  aw_r, bw_t, hub = 0.f;

  // ================= setup: masses, huber, expK caches =================
  {
    const float apt = a_mask[b*NP+t] * pc_a[((size_t)b*NP+t)*3+2];
    const float bpt = b_mask[b*NP+t] * pc_b[((size_t)b*NP+t)*3+2];
    float ra = apt, rv = bpt;
    #pragma unroll
    for (int o = 32; o; o >>= 1) { ra += __shfl_xor(ra, o); rv += __shfl_xor(rv, o); }
    if (lane == 0) { red[wid] = ra; red[8+wid] = rv; }
    __syncthreads();
    float asum = 0.f, bsum = 0.f;
    #pragma unroll
    for (int w = 0; w < 8; ++w) { asum += red[w]; bsum += red[8+w]; }
    const float e = asum - bsum, ae = fabsf(e);
    hub = (ae <= 1.f) ? 0.5f*e*e : (ae - 0.5f);
    sm[t]   = (apt > 0.f) ? apt/asum : 0.f;   // aw
    bw_l[t] = (bpt > 0.f) ? bpt/bsum : 0.f;
    __syncthreads();
    aw_r = sm[grow];
    bw_t = bw_l[t];
    const float ax = pc_a[((size_t)b*NP+grow)*3+0];
    const float ay = pc_a[((size_t)b*NP+grow)*3+1];
    const bool  va = aw_r > 0.f;
    #pragma unroll
    for (int cc = 0; cc < 16; ++cc) {
      float r[4];
      #pragma unroll
      for (int e2 = 0; e2 < 4; ++e2) {
        const int col = 32*cc + 4*chunk + e2;
        const float bx = pc_b[((size_t)b*NP+col)*3+0];
        const float by = pc_b[((size_t)b*NP+col)*3+1];
        const bool  vb = bw_l[col] > 0.f;
        const float dx = ax-bx, dy = ay-by;
        const float d  = sqrtf(dx*dx + dy*dy + 1e-12f);
        r[e2] = (va && vb) ? __expf((-INVEPS)*d) : 1.f;   // K=0 for masked pairs
      }
      eKreg[cc] = make_float4(r[0], r[1], r[2], r[3]);
    }
    const float bx0 = pc_b[((size_t)b*NP+t)*3+0];
    const float by0 = pc_b[((size_t)b*NP+t)*3+1];
    const bool  vb0 = bw_t > 0.f;
    #pragma unroll
    for (int i = 0; i < RPB; ++i) {
      const int row = rg*RPB + i;
      const float axi = pc_a[((size_t)b*NP+row)*3+0];  // wave-uniform -> scalar loads
      const float ayi = pc_a[((size_t)b*NP+row)*3+1];
      const bool  vai = sm[row] > 0.f;
      const float dx = axi-bx0, dy = ayi-by0;
      const float d  = sqrtf(dx*dx + dy*dy + 1e-12f);
      eKcol[i] = (vai && vb0) ? __expf((-INVEPS)*d) : 1.f;
    }
    rho_l[t] = 1.f;     // rho(0) = exp(logv=0) = 1
    __syncthreads();
  }

  // ================= main loop =================
  for (int k = 1; k <= ITERS; ++k) {
    const u32 tag = tag_of(k);
    const int par = k & 1;
    const u32* base = pack + ((size_t)par*NB + b)*RG*NP + t;

    // ---- B: u(k) = aw / sum_j ek*rho(k-1)
    {
      const float4* r4p = (const float4*)rho_l;
      float dot = 0.f;
      #pragma unroll
      for (int cc = 0; cc < 16; ++cc) {
        const float4 g4 = r4p[8*cc + chunk];
        const float4 kk = eKreg[cc];
        dot += kk.x*g4.x + kk.y*g4.y + kk.z*g4.z + kk.w*g4.w;
      }
      #pragma unroll
      for (int o = 4; o; o >>= 1) dot += __shfl_xor(dot, o);   // 8-lane row reduce
      if (chunk == 0) u_l[lrow] = aw_r / fmaxf(dot, 1e-38f);
    }
    __syncthreads();   // u_l ready (also: all rho_l reads done)

    // ---- C: publish packed col partial s(k) for col t; keep own value local
    float sc_own;
    {
      const float4* u4p = (const float4*)u_l;
      float sc = 0.f;
      #pragma unroll
      for (int i4 = 0; i4 < 16; ++i4) {
        const float4 uu = u4p[i4];
        sc += eKcol[4*i4+0]*uu.x + eKcol[4*i4+1]*uu.y
            + eKcol[4*i4+2]*uu.z + eKcol[4*i4+3]*uu.w;
      }
      sc_own = sc;
      st32(pack + (((size_t)par*NB + b)*RG + rg)*NP + t, pack_slot(sc, tag));
    }

    // ---- speculative gang issue, POST-publish (R7 change): samples the IC
    // at the instant near-lockstep peers are publishing too, so the first
    // check below catches most of them. (R0 issued this pre-B: stale by
    // construction, >=1 wasted re-sweep.)
    u32 q[RG];
    #pragma unroll
    for (int r = 0; r < RG; ++r)
      if (r != rg) q[r] = ld32(base + (size_t)r*NP);

    // ---- A: check results; sleep-free gang re-poll of laggards (R0-proven:
    // polls carry the data; the ~600cy IC RT is the natural backoff)
    {
      unsigned pend = 0xFFu & ~(1u << rg);
      long long sweeps = 0;
      while (true) {
        unsigned np = 0;
        #pragma unroll
        for (int r = 0; r < RG; ++r)
          if ((pend >> r) & 1u)
            if ((q[r] & 7u) != tag) np |= (1u << r);
        pend = np;
        if (!pend) break;
        #pragma unroll
        for (int r = 0; r < RG; ++r)        // re-issue ALL pending together
          if ((pend >> r) & 1u)
            q[r] = ld32(base + (size_t)r*NP);
        if (++sweeps > (1LL<<24)) break;    // fail visibly, never hang
      }
      float S = sc_own;
      #pragma unroll
      for (int r = 0; r < RG; ++r)
        if (r != rg) S += __uint_as_float(q[r]);   // <=7 ulp tag noise
      rho_l[t] = bw_t / fmaxf(S, 1e-38f);
    }
    __syncthreads();   // rho_l(k) ready for next B / epilogue
  }

  // ---- epilogue: ot partial = sum d^2 * u_i * ek * rho_j over my row slice
  float acc = 0.f;
  {
    const float ur = u_l[lrow];                  // u(50)
    const float4* r4p = (const float4*)rho_l;    // rho(50)
    #pragma unroll
    for (int cc = 0; cc < 16; ++cc) {
      const float4 g4 = r4p[8*cc + chunk];
      const float4 kk = eKreg[cc];
      const float ek[4] = {kk.x, kk.y, kk.z, kk.w};
      const float vv[4] = {g4.x, g4.y, g4.z, g4.w};
      #pragma unroll
      for (int e2 = 0; e2 < 4; ++e2) {
        const float lk = __logf(fmaxf(ek[e2], 1e-38f));  // d = -EPS*lk; masked: lk=0 -> d2=0
        const float d2 = (EPSV*lk)*(EPSV*lk);
        const float v  = d2 * ur * ek[e2] * vv[e2];
        acc += (ek[e2] > 0.f) ? v : 0.f;
      }
    }
  }
  // block-reduce, publish tagged epi, rg==0 gathers
  sm[t] = acc;
  __syncthreads();
  if (t < 64) {
    float v = 0.f;
    #pragma unroll
    for (int q2 = 0; q2 < 8; ++q2) v += sm[t*8+q2];
    #pragma unroll
    for (int o = 32; o; o >>= 1) v += __shfl_xor(v, o);
    if (t == 0) st64f(epi + (size_t)b*RG + rg, 51.f, v);
  }
  if (rg == 0 && t < RG) {     // gather: 8 lanes, poll + shfl-reduce
    float2 pr;
    long long spins = 0;
    do {
      pr = ld64f(epi + (size_t)b*RG + t);
      if (pr.x == 51.f) break;
      __builtin_amdgcn_s_sleep(1);
    } while (++spins < (1LL<<27));
    float v = pr.y;
    #pragma unroll
    for (int o = 4; o; o >>= 1) v += __shfl_xor(v, o);
    if (t == 0) out[b] = v + hub;
  }
}

extern "C" void kernel_launch(void* const* d_in, const int* in_sizes, int n_in,
                              void* d_out, int out_size, void* d_ws, size_t ws_size,
                              hipStream_t stream) {
  const float* a_mask = (const float*)d_in[0];
  const float* pc_a   = (const float*)d_in[1];
  const float* b_mask = (const float*)d_in[2];
  const float* pc_b   = (const float*)d_in[3];
  float* out = (float*)d_out;
  u32*    pack = (u32*)d_ws;                 // 1 MiB
  float2* epi  = (float2*)(pack + N_PACK);   // + 2 KiB
  (void)in_sizes; (void)n_in; (void)out_size; (void)ws_size;

  emd_kernel<<<NB*RG, NP, 0, stream>>>(a_mask, pc_a, b_mask, pc_b,
                                       pack, epi, out);
}